// Round 6
// baseline (258.281 us; speedup 1.0000x reference)
//
#include <hip/hip_runtime.h>
#include <hip/hip_bf16.h>
#include <math.h>

// Problem dims (fixed by setup_inputs)
#define E_   8
#define H_   768
#define I_   3072
#define T_   2048
#define NTOK (E_ * T_)

typedef __attribute__((ext_vector_type(8))) short bf16x8;   // 8 bf16 = 4 VGPRs
typedef __attribute__((ext_vector_type(4))) float f32x4;    // MFMA accum

typedef __attribute__((address_space(3))) void lds_void;
typedef const __attribute__((address_space(1))) void gl_void;

__device__ __forceinline__ void gload16(const void* g, void* l) {
  // 16B async global->LDS. LDS dest is wave-uniform base + lane*16.
  __builtin_amdgcn_global_load_lds((gl_void*)g, (lds_void*)l, 16, 0, 0);
}

// Compiler-only fence (0 instructions) + raw HW barrier. NOT __syncthreads():
// that would emit s_waitcnt vmcnt(0) and drain the prefetch pipeline (T4).
#define FENCE() asm volatile("" ::: "memory")
#define BAR()                         \
  do {                                \
    FENCE();                          \
    __builtin_amdgcn_s_barrier();     \
    FENCE();                          \
  } while (0)
#define VMWAIT(n) asm volatile("s_waitcnt vmcnt(" #n ")" ::: "memory")
// lgkmcnt(0) + sched_barrier(0): pin the MFMA cluster after the LDS drain
// (rule 18: hipcc can hoist reg-only MFMA past inline-asm lgkmcnt).
#define LGKM0()                                  \
  do {                                           \
    asm volatile("s_waitcnt lgkmcnt(0)" ::: "memory"); \
    __builtin_amdgcn_sched_barrier(0);           \
  } while (0)

#define MFMA16(a, b, c) __builtin_amdgcn_mfma_f32_16x16x32_bf16(a, b, c, 0, 0, 0)

// Fast GELU: v * sigmoid(1.5957691*(v + 0.044715 v^3)); |err| ~3e-4 << bf16
// storage error of the intermediate. (Round-2 verified, absmax 0.031.)
__device__ __forceinline__ float gelu_fast(float v) {
  float inner = v * fmaf(v * v, 0.044715f, 1.0f);
  float e = __builtin_amdgcn_exp2f(inner * -2.3022082f);
  return v * __builtin_amdgcn_rcpf(1.0f + e);
}

// ---------------------------------------------------------------------------
// fp32 -> bf16 elementwise convert
// ---------------------------------------------------------------------------
__global__ __launch_bounds__(256) void cvt_bf16_kernel(
    const float* __restrict__ in, __hip_bfloat16* __restrict__ out) {
  int i = (blockIdx.x * 256 + threadIdx.x) * 4;
  float4 v = *(const float4*)(in + i);
  __align__(8) __hip_bfloat16 t[4];
  t[0] = __float2bfloat16(v.x);
  t[1] = __float2bfloat16(v.y);
  t[2] = __float2bfloat16(v.z);
  t[3] = __float2bfloat16(v.w);
  *(ushort4*)(out + i) = *(const ushort4*)t;
}

// ---------------------------------------------------------------------------
// [E][R][C] fp32 -> [E][C][R] bf16 (64x64 LDS tiles; ushort2 stores)
// ---------------------------------------------------------------------------
__global__ __launch_bounds__(256) void transpose_cvt_kernel(
    const float* __restrict__ src, __hip_bfloat16* __restrict__ dst,
    int R, int C) {
  __shared__ __hip_bfloat16 tile[64][65];
  int e  = blockIdx.z;
  int c0 = blockIdx.x * 64;
  int r0 = blockIdx.y * 64;
  const float* s = src + (size_t)e * R * C;
  __hip_bfloat16* d = dst + (size_t)e * R * C;
  int tx = threadIdx.x & 63, ty = threadIdx.x >> 6;
#pragma unroll
  for (int r = ty; r < 64; r += 4)
    tile[r][tx] = __float2bfloat16(s[(size_t)(r0 + r) * C + c0 + tx]);
  __syncthreads();
  // Vectorized write: lane handles 2 consecutive output cols (ushort2 = 4B).
  int tx2 = threadIdx.x & 31;
  int ty2 = threadIdx.x >> 5;
#pragma unroll
  for (int rr = ty2; rr < 64; rr += 8) {
    ushort2 v;
    v.x = *(const ushort*)&tile[2 * tx2][rr];
    v.y = *(const ushort*)&tile[2 * tx2 + 1][rr];
    *(ushort2*)&d[(size_t)(c0 + rr) * R + r0 + 2 * tx2] = v;
  }
}

// ---------------------------------------------------------------------------
// Grouped GEMM — faithful m201 8-phase template (T1+T2+T3+T4+T5).
// 256x256 tile, BK=64, 2 K-tiles/iteration, 512 thr = 8 waves (2M x 4N),
// per-wave 128x64 out, mfma_f32_16x16x32_bf16.
//
// LDS: sA/sB[2 buf][2 half][128][64] bf16 = 128 KiB (buf0 = even tiles,
// buf1 = odd). A-half h = rows {(r>>6)&1==h}; B-half h = cols {(n>>5)&1==h}.
//
// Per phase: {ds_read quadrant frags -> BAR -> lgkmcnt(0) -> setprio(1) ->
// 16 MFMA -> setprio(0) -> BAR}. Reads are issued BEFORE the barrier so the
// LDS drain staggers MFMA start across waves (read-drain overlaps other
// waves' MFMA — the mechanism behind m201's 62% MfmaUtil vs our 33%).
//
// Quadrants: P1..P4 = tile t0 (buf0) (0,0)(0,1)(1,1)(1,0); P5..P8 = t1
// (buf1). Reads/phase: 12,4,8,0,12,4,8,0 (A/B halves read once per tile,
// reused from regs). Stages (2 gloads each), targeting the region freed one
// phase earlier:  P1: buf1.A1<-t1.A1 (always)  P2: buf0.A0<-t2  P3: buf0.B0
// P4: buf0.B1  P5: buf0.A1  P6: buf1.A0<-t3  P7: buf1.B0  P8: buf1.B1.
// WAR: every stage target's last reader drained (lgkm0) >=1 BAR-pair before
// the stage issues — verified phase-by-phase.
//
// Counted waits, ONCE per K-tile (never 0 mid-loop), FIFO ledger:
//   entering P1: outstanding = t1.{A0,B0,B1} = 6 loads.
//   P4: +{A1,t2.A0,B0,B1} = 14 -> VMWAIT(6): all of t1 landed (P5-P7 safe).
//   P8: <=14 again        -> VMWAIT(6): all of t2 landed (next P1-P3 safe).
// Prologue: stage t0 (8), t1.{A0,B0,B1} (6), VMWAIT(6) (t0 lands), BAR.
// Epilogue iter (pf=false): P1 stages t1.A1; P4 VMWAIT(2) (t1.A0,B0,B1);
// P6 VMWAIT(0) (t1.A1).
//
// T2 swizzle: LDS linear (gload_lds), global source col-group pre-swizzled
// cg = c8 ^ (lr&7); reads XOR the same. Bank conflicts measured 0 (round 3).
// T1 XCD swizzle: both grids are multiples of 8.
// ---------------------------------------------------------------------------
template <int K, int N, bool GELU>
__global__ __launch_bounds__(512, 2) void gemm8q_kernel(
    const __hip_bfloat16* __restrict__ A,
    const __hip_bfloat16* __restrict__ B,
    const float* __restrict__ bias,
    __hip_bfloat16* __restrict__ out) {
  constexpr int MT  = T_ / 256;
  constexpr int NT  = N / 256;
  constexpr int KT  = K / 64;
  constexpr int NIT = KT / 2;  // 2 K-tiles per iteration
  static_assert(KT % 2 == 0, "even K-tile count required");

  __shared__ __hip_bfloat16 sA[2][2][128][64];
  __shared__ __hip_bfloat16 sB[2][2][128][64];

  // T1: bijective XCD swizzle (gridDim.x % 8 == 0 for both GEMMs).
  int nwg = gridDim.x;
  int b0  = blockIdx.x;
  int bid = (b0 & 7) * (nwg >> 3) + (b0 >> 3);

  int e   = bid / (MT * NT);
  int rr_ = bid % (MT * NT);
  int bm  = rr_ / NT;
  int bn  = rr_ % NT;

  const __hip_bfloat16* Ae = A + (size_t)e * T_ * K + (size_t)bm * 256 * K;
  const __hip_bfloat16* Be = B + (size_t)e * N  * K + (size_t)bn * 256 * K;

  int tid  = threadIdx.x;
  int lane = tid & 63;
  int wid  = tid >> 6;
  int wr   = wid >> 2;   // 0..1 (M)
  int wc   = wid & 3;    // 0..3 (N)
  int l15  = lane & 15;
  int l16h = lane >> 4;  // 0..3

  // --- staging geometry: idx = pass*512 + tid, lr = idx>>3, c8 = idx&7
  int i0 = tid, i1 = 512 + tid;
  int lr0 = i0 >> 3, c80 = i0 & 7, cg0 = c80 ^ (lr0 & 7);
  int lr1 = i1 >> 3, c81 = i1 & 7, cg1 = c81 ^ (lr1 & 7);
  int rA0 = ((lr0 >> 6) << 7) | (lr0 & 63);  // + h<<6
  int rA1 = ((lr1 >> 6) << 7) | (lr1 & 63);
  int rB0 = ((lr0 >> 5) << 6) | (lr0 & 31);  // + h<<5
  int rB1 = ((lr1 >> 5) << 6) | (lr1 & 31);

  auto stageA = [&](int buf, int h, int kt) {
    const __hip_bfloat16* g = Ae + (size_t)kt * 64;
    gload16(g + (size_t)(rA0 | (h << 6)) * K + cg0 * 8, &sA[buf][h][lr0][c80 * 8]);
    gload16(g + (size_t)(rA1 | (h << 6)) * K + cg1 * 8, &sA[buf][h][lr1][c81 * 8]);
  };
  auto stageB = [&](int buf, int h, int kt) {
    const __hip_bfloat16* g = Be + (size_t)kt * 64;
    gload16(g + (size_t)(rB0 | (h << 5)) * K + cg0 * 8, &sB[buf][h][lr0][c80 * 8]);
    gload16(g + (size_t)(rB1 | (h << 5)) * K + cg1 * 8, &sB[buf][h][lr1][c81 * 8]);
  };

  // --- fragment-read geometry (T2 read-side XOR)
  int laBase = wr * 64 + l15;  // + mf*16, within A-half
  int lbBase = wc * 32 + l15;  // + nf*16, within B-half
  int s7   = l15 & 7;
  int cgr0 = ((0 | l16h) ^ s7) * 8;  // ks=0 element offset
  int cgr1 = ((4 | l16h) ^ s7) * 8;  // ks=1

  f32x4 acc[8][4] = {};  // [mh*4+mf][2*nh+nf]
  bf16x8 af[4][2], bfv[4][2];

  auto readA = [&](int buf, int h) {
#pragma unroll
    for (int mf = 0; mf < 4; ++mf) {
      int la = laBase + mf * 16;
      af[mf][0] = *(const bf16x8*)&sA[buf][h][la][cgr0];
      af[mf][1] = *(const bf16x8*)&sA[buf][h][la][cgr1];
    }
  };
  auto readB = [&](int buf, int h) {  // into bfv[2h], bfv[2h+1]
#pragma unroll
    for (int nf = 0; nf < 2; ++nf) {
      int lb = lbBase + nf * 16;
      bfv[2 * h + nf][0] = *(const bf16x8*)&sB[buf][h][lb][cgr0];
      bfv[2 * h + nf][1] = *(const bf16x8*)&sB[buf][h][lb][cgr1];
    }
  };
  auto mmaQ = [&](int mh, int nh) {  // 16 MFMA: quadrant (mh, nh)
    __builtin_amdgcn_s_setprio(1);
#pragma unroll
    for (int mf = 0; mf < 4; ++mf)
#pragma unroll
      for (int nf = 2 * nh; nf < 2 * nh + 2; ++nf) {
        acc[4 * mh + mf][nf] = MFMA16(af[mf][0], bfv[nf][0], acc[4 * mh + mf][nf]);
        acc[4 * mh + mf][nf] = MFMA16(af[mf][1], bfv[nf][1], acc[4 * mh + mf][nf]);
      }
    __builtin_amdgcn_s_setprio(0);
  };

  // ---- prologue: t0 fully (8 loads) + t1.{A0,B0,B1} (6 loads)
  stageA(0, 0, 0);
  stageB(0, 0, 0);
  stageB(0, 1, 0);
  stageA(0, 1, 0);
  stageA(1, 0, 1);
  stageB(1, 0, 1);
  stageB(1, 1, 1);
  VMWAIT(6);  // t0 landed; t1.{A0,B0,B1} (6) remain in flight
  BAR();

  auto iter = [&](int t0, bool pf) {
    // P1: t0 Q(0,0) — reads A0(8)+B0(4); stage buf1.A1 <- t1.A1 (always)
    readA(0, 0);
    readB(0, 0);
    stageA(1, 1, t0 + 1);
    BAR(); LGKM0(); mmaQ(0, 0); BAR();
    // P2: t0 Q(0,1) — reads B1(4); stage buf0.A0 <- t2.A0
    readB(0, 1);
    if (pf) stageA(0, 0, t0 + 2);
    BAR(); LGKM0(); mmaQ(0, 1); BAR();
    // P3: t0 Q(1,1) — reads A1(8, af overwrite); stage buf0.B0
    readA(0, 1);
    if (pf) stageB(0, 0, t0 + 2);
    BAR(); LGKM0(); mmaQ(1, 1); BAR();
    // P4: t0 Q(1,0) — 0 reads; stage buf0.B1; K-tile wait
    if (pf) {
      stageB(0, 1, t0 + 2);
      VMWAIT(6);  // lands ALL of t1 (P5-P7 consumers)
    } else {
      VMWAIT(2);  // epilogue: lands t1.{A0,B0,B1}
    }
    BAR(); mmaQ(1, 0); BAR();
    // P5: t1 Q(0,0) — reads A0(8)+B0(4); stage buf0.A1
    readA(1, 0);
    readB(1, 0);
    if (pf) stageA(0, 1, t0 + 2);
    BAR(); LGKM0(); mmaQ(0, 0); BAR();
    // P6: t1 Q(0,1) — reads B1(4); stage buf1.A0 <- t3.A0
    readB(1, 1);
    if (pf) stageA(1, 0, t0 + 3);
    else VMWAIT(0);  // epilogue: lands t1.A1 (P7 consumer)
    BAR(); LGKM0(); mmaQ(0, 1); BAR();
    // P7: t1 Q(1,1) — reads A1(8); stage buf1.B0
    readA(1, 1);
    if (pf) stageB(1, 0, t0 + 3);
    BAR(); LGKM0(); mmaQ(1, 1); BAR();
    // P8: t1 Q(1,0) — 0 reads; stage buf1.B1; K-tile wait
    if (pf) {
      stageB(1, 1, t0 + 3);
      VMWAIT(6);  // lands ALL of t2 (next-iter P1-P3 consumers)
    }
    BAR(); mmaQ(1, 0); BAR();
  };

  for (int it = 0; it < NIT - 1; ++it) iter(2 * it, true);
  iter(2 * (NIT - 1), false);  // peeled epilogue iteration

  // ---- epilogue: +bias, optional GELU, bf16 store.
  // C/D mapping (m89): col = lane&15, row = (lane>>4)*4 + r.
  const float* be = bias + (size_t)e * N + bn * 256;
  __hip_bfloat16* oe =
      out + (size_t)e * T_ * N + (size_t)(bm * 256) * N + bn * 256;
  int r4 = l16h * 4;
#pragma unroll
  for (int mi = 0; mi < 8; ++mi) {
    int mh = mi >> 2, mf = mi & 3;
    int rowb = wr * 128 + mh * 64 + mf * 16 + r4;
#pragma unroll
    for (int nf = 0; nf < 4; ++nf) {
      int cc   = wc * 64 + nf * 16 + l15;
      float bv = be[cc];
#pragma unroll
      for (int r = 0; r < 4; ++r) {
        float v = acc[mi][nf][r] + bv;
        if (GELU) v = gelu_fast(v);
        oe[(size_t)(rowb + r) * N + cc] = __float2bfloat16(v);
      }
    }
  }
}

// ---------------------------------------------------------------------------
// Residual + LayerNorm: one 256-thread block per token row (H=768 = 3*256).
// ---------------------------------------------------------------------------
__global__ __launch_bounds__(256) void ln_kernel(
    const __hip_bfloat16* __restrict__ yraw, const float* __restrict__ x,
    const float* __restrict__ gamma, const float* __restrict__ beta,
    float* __restrict__ out) {
  int row  = blockIdx.x;
  int tid  = threadIdx.x;
  int lane = tid & 63, wid = tid >> 6;
  const __hip_bfloat16* yr = yraw + (size_t)row * H_;
  const float* xr = x + (size_t)row * H_;

  float v[3];
  float s = 0.f, s2 = 0.f;
#pragma unroll
  for (int j = 0; j < 3; ++j) {
    int c   = tid + j * 256;
    float t = __bfloat162float(yr[c]) + xr[c];
    v[j] = t;
    s += t;
    s2 += t * t;
  }
#pragma unroll
  for (int o = 32; o > 0; o >>= 1) {
    s  += __shfl_down(s, o);
    s2 += __shfl_down(s2, o);
  }
  __shared__ float ls[4], ls2[4];
  if (lane == 0) { ls[wid] = s; ls2[wid] = s2; }
  __syncthreads();
  float tot  = ls[0] + ls[1] + ls[2] + ls[3];
  float tot2 = ls2[0] + ls2[1] + ls2[2] + ls2[3];
  float mean = tot * (1.0f / 768.0f);
  float var  = tot2 * (1.0f / 768.0f) - mean * mean;
  float inv  = rsqrtf(var + 1e-12f);
  float* orow = out + (size_t)row * H_;
#pragma unroll
  for (int j = 0; j < 3; ++j) {
    int c = tid + j * 256;
    orow[c] = (v[j] - mean) * inv * gamma[c] + beta[c];
  }
}

// ---------------------------------------------------------------------------
extern "C" void kernel_launch(void* const* d_in, const int* in_sizes, int n_in,
                              void* d_out, int out_size, void* d_ws,
                              size_t ws_size, hipStream_t stream) {
  const float* x     = (const float*)d_in[0];  // [N, H]
  const float* w1    = (const float*)d_in[1];  // [E, H, I]
  const float* b1    = (const float*)d_in[2];  // [E, I]
  const float* w2    = (const float*)d_in[3];  // [E, I, H]
  const float* b2    = (const float*)d_in[4];  // [E, H]
  const float* gamma = (const float*)d_in[5];  // [H]
  const float* beta  = (const float*)d_in[6];  // [H]
  float* out = (float*)d_out;

  // Workspace layout (192 MiB):
  //   w1t  [E][I][H] bf16 @ 0           (37,748,736 B)
  //   w2t  [E][H][I] bf16 @ 37748736    (37,748,736 B)
  //   x_bf [N][H]    bf16 @ 75497472    (25,165,824 B; aliased by yraw)
  //   inter[E][T][I] bf16 @ 100663296   (100,663,296 B)
  char* ws = (char*)d_ws;
  __hip_bfloat16* w1t   = (__hip_bfloat16*)(ws);
  __hip_bfloat16* w2t   = (__hip_bfloat16*)(ws + 37748736);
  __hip_bfloat16* x_bf  = (__hip_bfloat16*)(ws + 75497472);
  __hip_bfloat16* inter = (__hip_bfloat16*)(ws + 100663296);
  __hip_bfloat16* yraw  = x_bf;  // x_bf dead after GEMM1; safe alias

  cvt_bf16_kernel<<<(NTOK * H_) / (256 * 4), 256, 0, stream>>>(x, x_bf);
  transpose_cvt_kernel<<<dim3(I_ / 64, H_ / 64, E_), 256, 0, stream>>>(
      w1, w1t, H_, I_);
  transpose_cvt_kernel<<<dim3(H_ / 64, I_ / 64, E_), 256, 0, stream>>>(
      w2, w2t, I_, H_);
  // GEMM1 + bias + GELU -> inter : 8*8*12 = 768 blocks (3 CU rounds)
  gemm8q_kernel<H_, I_, true>
      <<<E_ * (T_ / 256) * (I_ / 256), 512, 0, stream>>>(x_bf, w1t, b1, inter);
  // GEMM2 + bias -> yraw : 8*8*3 = 192 blocks
  gemm8q_kernel<I_, H_, false>
      <<<E_ * (T_ / 256) * (H_ / 256), 512, 0, stream>>>(inter, w2t, b2, yraw);
  ln_kernel<<<NTOK, 256, 0, stream>>>(yraw, x, gamma, beta, out);
}